// Round 1
// baseline (41755.099 us; speedup 1.0000x reference)
//
#include <hip/hip_runtime.h>
#include <math.h>

#define N_NODES 100000
#define N_EDGES 3200000
#define IN_CH   500
#define HID     64
#define OUT_CH  40
#define K_HOPS  10
#define BN_EPS  1e-5f

// ---------------- workspace layout (bytes) ----------------
// flag      : [0, 512)
// src32     : [512, 512 + E*4)                    = 12.8 MB
// dst32     : [12800512, 25600512)                = 12.8 MB
// dinv      : [25600512, 26000512)                = 0.4 MB
// norm      : [26000512, 38800512)                = 12.8 MB
// bufA      : [38800512, 54800512)                = 16 MB (N*40 f32)
// bufB      : [54800512, 70800512)                = 16 MB
#define OFF_FLAG 0
#define OFF_SRC  512
#define OFF_DST  12800512
#define OFF_DINV 25600512
#define OFF_NORM 26000512
#define OFF_A    38800512
#define OFF_B    54800512

// Detect whether edge_index is stored as int64 (odd 32-bit words all zero)
// or int32. Values are in [0, 100000) so int64 high words are 0.
__global__ void detect_kernel(const unsigned int* __restrict__ ei, int* __restrict__ flag) {
    if (blockIdx.x == 0 && threadIdx.x == 0) {
        int is64 = 1;
        for (int i = 1; i < 64; i += 2) {
            if (ei[i] != 0u) { is64 = 0; break; }
        }
        *flag = is64;
    }
}

__global__ void convert_edges_kernel(const int* __restrict__ ei, int* __restrict__ src,
                                     int* __restrict__ dst, const int* __restrict__ flag) {
    int e = blockIdx.x * blockDim.x + threadIdx.x;
    if (e >= N_EDGES) return;
    if (*flag) {  // int64 little-endian: low words at even indices
        src[e] = ei[2 * e];
        dst[e] = ei[2 * (N_EDGES + e)];
    } else {
        src[e] = ei[e];
        dst[e] = ei[N_EDGES + e];
    }
}

__global__ void deg_init_kernel(float* __restrict__ dinv) {
    int i = blockIdx.x * blockDim.x + threadIdx.x;
    if (i < N_NODES) dinv[i] = 1.0f;  // self-loop
}

__global__ void deg_acc_kernel(const int* __restrict__ dst, float* __restrict__ dinv) {
    int e = blockIdx.x * blockDim.x + threadIdx.x;
    if (e < N_EDGES) atomicAdd(&dinv[dst[e]], 1.0f);
}

__global__ void deg_fin_kernel(float* __restrict__ dinv) {
    int i = blockIdx.x * blockDim.x + threadIdx.x;
    if (i < N_NODES) dinv[i] = rsqrtf(dinv[i]);  // deg >= 1 always
}

__global__ void norm_kernel(const int* __restrict__ src, const int* __restrict__ dst,
                            const float* __restrict__ dinv, float* __restrict__ nrm) {
    int e = blockIdx.x * blockDim.x + threadIdx.x;
    if (e < N_EDGES) nrm[e] = dinv[src[e]] * dinv[dst[e]];
}

// Fused MLP stem: h = relu(bn(x@W1^T + b1)); z = h@W2^T + b2.
// Writes A = z, hidden = temp[0]*z, B = dinv^2 * z (self-loop pre-init for hop 0).
// 16 nodes per block, 256 threads, K tiled in 4 chunks of 125.
__launch_bounds__(256)
__global__ void stem_kernel(const float* __restrict__ x, const float* __restrict__ W1,
                            const float* __restrict__ b1, const float* __restrict__ W2,
                            const float* __restrict__ b2, const float* __restrict__ gamma,
                            const float* __restrict__ beta, const float* __restrict__ mean,
                            const float* __restrict__ var, const float* __restrict__ temp,
                            const float* __restrict__ dinv, float* __restrict__ A,
                            float* __restrict__ B, float* __restrict__ hidden) {
    __shared__ float4 xs4[16 * 125];      // 32 KB: full x tile [16][500]
    __shared__ float  wts[125 * 65];      // 32.5 KB: W1 chunk transposed, padded
    __shared__ float  hs[16 * 65];        // 4.2 KB: hidden activations, padded
    __shared__ float  w2s[40 * 65];       // 10.4 KB: W2, padded

    const float* xs = (const float*)xs4;
    int t = threadIdx.x;
    int node0 = blockIdx.x * 16;

    // stage x tile (coalesced float4)
    const float4* xg = (const float4*)(x + (long long)node0 * IN_CH);
    for (int i = t; i < 16 * 125; i += 256) xs4[i] = xg[i];
    // stage W2 (coalesced read, padded LDS write)
    for (int i = t; i < OUT_CH * HID; i += 256) {
        int o = i >> 6, hh = i & 63;
        w2s[o * 65 + hh] = W2[i];
    }

    int h = t & 63, grp = t >> 6;       // grp handles nodes grp*4 .. grp*4+3
    float acc0 = 0.f, acc1 = 0.f, acc2 = 0.f, acc3 = 0.f;

    for (int kc = 0; kc < 4; ++kc) {
        __syncthreads();
        // stage W1 chunk transposed: wts[kk*65+h] = W1[h][kc*125+kk] (coalesced along k)
        for (int i = t; i < HID * 125; i += 256) {
            int hh = i / 125, kk = i - hh * 125;
            wts[kk * 65 + hh] = W1[hh * IN_CH + kc * 125 + kk];
        }
        __syncthreads();
        const float* xr0 = xs + (grp * 4 + 0) * IN_CH + kc * 125;
        const float* xr1 = xs + (grp * 4 + 1) * IN_CH + kc * 125;
        const float* xr2 = xs + (grp * 4 + 2) * IN_CH + kc * 125;
        const float* xr3 = xs + (grp * 4 + 3) * IN_CH + kc * 125;
        #pragma unroll 5
        for (int kk = 0; kk < 125; ++kk) {
            float wv = wts[kk * 65 + h];
            acc0 = fmaf(xr0[kk], wv, acc0);
            acc1 = fmaf(xr1[kk], wv, acc1);
            acc2 = fmaf(xr2[kk], wv, acc2);
            acc3 = fmaf(xr3[kk], wv, acc3);
        }
    }

    // BN (folded) + ReLU
    float sc  = rsqrtf(var[h] + BN_EPS) * gamma[h];
    float off = beta[h] - mean[h] * sc;
    float b1h = b1[h];
    hs[(grp * 4 + 0) * 65 + h] = fmaxf((acc0 + b1h) * sc + off, 0.f);
    hs[(grp * 4 + 1) * 65 + h] = fmaxf((acc1 + b1h) * sc + off, 0.f);
    hs[(grp * 4 + 2) * 65 + h] = fmaxf((acc2 + b1h) * sc + off, 0.f);
    hs[(grp * 4 + 3) * 65 + h] = fmaxf((acc3 + b1h) * sc + off, 0.f);
    __syncthreads();

    // second GEMM: z[n][o] = b2[o] + sum_h hs[n][h]*W2[o][h]; write A/B/hidden
    float t0 = temp[0];
    for (int idx = t; idx < 16 * OUT_CH; idx += 256) {
        int n = idx / OUT_CH, o = idx - n * OUT_CH;
        const float* hr = hs + n * 65;
        const float* wr = w2s + o * 65;
        float zv = b2[o];
        #pragma unroll 8
        for (int hh = 0; hh < HID; ++hh) zv = fmaf(hr[hh], wr[hh], zv);
        int g = node0 + n;
        float dv = dinv[g];
        A[(long long)g * OUT_CH + o] = zv;
        hidden[(long long)g * OUT_CH + o] = t0 * zv;
        B[(long long)g * OUT_CH + o] = dv * dv * zv;
    }
}

// One hop of propagation: B[dst] += norm * A[src], 8 channels per thread.
__launch_bounds__(256)
__global__ void scatter_kernel(const int* __restrict__ src, const int* __restrict__ dst,
                               const float* __restrict__ nrm, const float* __restrict__ A,
                               float* __restrict__ B) {
    int t = blockIdx.x * blockDim.x + threadIdx.x;   // < E*5 = 16M
    int e = t / 5;
    int g = t - e * 5;
    if (e >= N_EDGES) return;
    int s = src[e], d = dst[e];
    float w = nrm[e];
    const float4* a = (const float4*)(A + (long long)s * OUT_CH + g * 8);
    float4 v0 = a[0], v1 = a[1];
    float* bp = B + (long long)d * OUT_CH + g * 8;
    atomicAdd(bp + 0, w * v0.x); atomicAdd(bp + 1, w * v0.y);
    atomicAdd(bp + 2, w * v0.z); atomicAdd(bp + 3, w * v0.w);
    atomicAdd(bp + 4, w * v1.x); atomicAdd(bp + 5, w * v1.y);
    atomicAdd(bp + 6, w * v1.z); atomicAdd(bp + 7, w * v1.w);
}

// hidden += temp[k]*B; if do_prep: Anext = dinv^2 * B (self-loop pre-init of next hop)
__launch_bounds__(256)
__global__ void accum_kernel(float* __restrict__ hidden, const float* __restrict__ Bv,
                             float* __restrict__ Anext, const float* __restrict__ dinv,
                             const float* __restrict__ temp, int k, int do_prep) {
    int i = blockIdx.x * blockDim.x + threadIdx.x;   // float4 index, < N*10
    if (i >= N_NODES * 10) return;
    float tk = temp[k];
    float4 v = ((const float4*)Bv)[i];
    float4* hp = (float4*)hidden;
    float4 hv = hp[i];
    hv.x += tk * v.x; hv.y += tk * v.y; hv.z += tk * v.z; hv.w += tk * v.w;
    hp[i] = hv;
    if (do_prep) {
        int node = i / 10;
        float dv = dinv[node];
        float d2 = dv * dv;
        float4 o;
        o.x = d2 * v.x; o.y = d2 * v.y; o.z = d2 * v.z; o.w = d2 * v.w;
        ((float4*)Anext)[i] = o;
    }
}

// In-place log_softmax over the 40-channel rows of d_out.
__launch_bounds__(256)
__global__ void lsm_kernel(float* __restrict__ out) {
    int n = blockIdx.x * blockDim.x + threadIdx.x;
    if (n >= N_NODES) return;
    float4* p = (float4*)(out + (long long)n * OUT_CH);
    float4 v[10];
    float mx = -INFINITY;
    #pragma unroll
    for (int i = 0; i < 10; ++i) {
        v[i] = p[i];
        mx = fmaxf(mx, fmaxf(fmaxf(v[i].x, v[i].y), fmaxf(v[i].z, v[i].w)));
    }
    float sum = 0.f;
    #pragma unroll
    for (int i = 0; i < 10; ++i) {
        sum += expf(v[i].x - mx) + expf(v[i].y - mx) + expf(v[i].z - mx) + expf(v[i].w - mx);
    }
    float l = mx + logf(sum);
    #pragma unroll
    for (int i = 0; i < 10; ++i) {
        v[i].x -= l; v[i].y -= l; v[i].z -= l; v[i].w -= l;
        p[i] = v[i];
    }
}

extern "C" void kernel_launch(void* const* d_in, const int* in_sizes, int n_in,
                              void* d_out, int out_size, void* d_ws, size_t ws_size,
                              hipStream_t stream) {
    const float* x     = (const float*)d_in[0];
    const void*  ei    = d_in[1];
    const float* W1    = (const float*)d_in[2];
    const float* b1    = (const float*)d_in[3];
    const float* W2    = (const float*)d_in[4];
    const float* b2    = (const float*)d_in[5];
    const float* gamma = (const float*)d_in[6];
    const float* beta  = (const float*)d_in[7];
    const float* mean  = (const float*)d_in[8];
    const float* var   = (const float*)d_in[9];
    const float* temp  = (const float*)d_in[10];
    float* out = (float*)d_out;

    char* ws = (char*)d_ws;
    int*   flag = (int*)(ws + OFF_FLAG);
    int*   src  = (int*)(ws + OFF_SRC);
    int*   dst  = (int*)(ws + OFF_DST);
    float* dinv = (float*)(ws + OFF_DINV);
    float* nrm  = (float*)(ws + OFF_NORM);
    float* A    = (float*)(ws + OFF_A);
    float* B    = (float*)(ws + OFF_B);

    detect_kernel<<<1, 64, 0, stream>>>((const unsigned int*)ei, flag);
    convert_edges_kernel<<<(N_EDGES + 255) / 256, 256, 0, stream>>>((const int*)ei, src, dst, flag);
    deg_init_kernel<<<(N_NODES + 255) / 256, 256, 0, stream>>>(dinv);
    deg_acc_kernel<<<(N_EDGES + 255) / 256, 256, 0, stream>>>(dst, dinv);
    deg_fin_kernel<<<(N_NODES + 255) / 256, 256, 0, stream>>>(dinv);
    norm_kernel<<<(N_EDGES + 255) / 256, 256, 0, stream>>>(src, dst, dinv, nrm);

    stem_kernel<<<N_NODES / 16, 256, 0, stream>>>(x, W1, b1, W2, b2, gamma, beta,
                                                  mean, var, temp, dinv, A, B, out);

    float* cur = A;  // holds z
    float* nxt = B;  // pre-initialized with dinv^2 * z
    for (int k = 0; k < K_HOPS; ++k) {
        scatter_kernel<<<(N_EDGES * 5) / 256, 256, 0, stream>>>(src, dst, nrm, cur, nxt);
        accum_kernel<<<(N_NODES * 10 + 255) / 256, 256, 0, stream>>>(
            out, nxt, cur, dinv, temp, k + 1, (k < K_HOPS - 1) ? 1 : 0);
        float* t2 = cur; cur = nxt; nxt = t2;
    }

    lsm_kernel<<<(N_NODES + 255) / 256, 256, 0, stream>>>(out);
}

// Round 2
// 2101.806 us; speedup vs baseline: 19.8663x; 19.8663x over previous
//
#include <hip/hip_runtime.h>
#include <math.h>

#define N_NODES 100000
#define N_EDGES 3200000
#define IN_CH   500
#define HID     64
#define OUT_CH  40
#define K_HOPS  10
#define BN_EPS  1e-5f
#define NB_SCAN ((N_NODES + 255) / 256)   // 391

// ---------------- workspace layout (bytes) ----------------
#define OFF_FLAG    0           // 512
#define OFF_DEG     512         // N*4 = 400000        -> 400512
#define OFF_ROWPTR  400896      // (N+1)*4 = 400004    -> 800900
#define OFF_CURSOR  801024      // N*4                 -> 1201024
#define OFF_DINV    1201024     // N*4                 -> 1601024
#define OFF_BSUM    1601024     // 2048                -> 1603072
#define OFF_BSCAN   1603072     // 2048                -> 1605632
#define OFF_CSRE    1605632     // E*8 = 25.6MB        -> 27205632  (int2 {src, w})
#define OFF_A       27205632    // N*40*4 = 16MB       -> 43205632
#define OFF_B       43205632    // 16MB                -> 59205632

// Detect whether edge_index is stored as int64 (odd 32-bit words all zero)
// or int32. Values are in [0, 100000) so int64 high words are 0.
__global__ void detect_kernel(const unsigned int* __restrict__ ei, int* __restrict__ flag) {
    if (blockIdx.x == 0 && threadIdx.x == 0) {
        int is64 = 1;
        for (int i = 1; i < 64; i += 2) {
            if (ei[i] != 0u) { is64 = 0; break; }
        }
        *flag = is64;
    }
}

__global__ void zero_deg_kernel(int* __restrict__ deg) {
    int i = blockIdx.x * blockDim.x + threadIdx.x;
    if (i < N_NODES) deg[i] = 0;
}

__global__ void deg_kernel(const int* __restrict__ ei, const int* __restrict__ flag,
                           int* __restrict__ deg) {
    int e = blockIdx.x * blockDim.x + threadIdx.x;
    if (e >= N_EDGES) return;
    int d = (*flag) ? ei[2 * (N_EDGES + e)] : ei[N_EDGES + e];
    atomicAdd(&deg[d], 1);
}

// 3-kernel exclusive prefix scan of deg -> rowptr
__global__ void scan_reduce_kernel(const int* __restrict__ deg, int* __restrict__ bsum) {
    __shared__ int s[256];
    int i = blockIdx.x * 256 + threadIdx.x;
    s[threadIdx.x] = (i < N_NODES) ? deg[i] : 0;
    __syncthreads();
    for (int off = 128; off > 0; off >>= 1) {
        if (threadIdx.x < off) s[threadIdx.x] += s[threadIdx.x + off];
        __syncthreads();
    }
    if (threadIdx.x == 0) bsum[blockIdx.x] = s[0];
}

__global__ void scan_bsums_kernel(const int* __restrict__ bsum, int* __restrict__ bscan) {
    __shared__ int s[512];
    int t = threadIdx.x;
    int orig = (t < NB_SCAN) ? bsum[t] : 0;
    s[t] = orig;
    __syncthreads();
    for (int off = 1; off < 512; off <<= 1) {
        int v = (t >= off) ? s[t - off] : 0;
        __syncthreads();
        s[t] += v;
        __syncthreads();
    }
    if (t < NB_SCAN) bscan[t] = s[t] - orig;   // exclusive
}

__global__ void scan_final_kernel(const int* __restrict__ deg, const int* __restrict__ bscan,
                                  int* __restrict__ rowptr) {
    __shared__ int s[256];
    int i = blockIdx.x * 256 + threadIdx.x;
    int v = (i < N_NODES) ? deg[i] : 0;
    s[threadIdx.x] = v;
    __syncthreads();
    for (int off = 1; off < 256; off <<= 1) {
        int u = (threadIdx.x >= off) ? s[threadIdx.x - off] : 0;
        __syncthreads();
        s[threadIdx.x] += u;
        __syncthreads();
    }
    if (i < N_NODES) rowptr[i] = bscan[blockIdx.x] + s[threadIdx.x] - v;
    if (i == N_NODES - 1) rowptr[N_NODES] = bscan[blockIdx.x] + s[threadIdx.x];
}

// dinv = rsqrt(deg+1) (self-loop); cursor = rowptr
__global__ void finalize_kernel(const int* __restrict__ deg, const int* __restrict__ rowptr,
                                float* __restrict__ dinv, int* __restrict__ cursor) {
    int i = blockIdx.x * blockDim.x + threadIdx.x;
    if (i >= N_NODES) return;
    dinv[i] = rsqrtf((float)deg[i] + 1.0f);
    cursor[i] = rowptr[i];
}

// CSR fill: csre[pos] = {src, w = dinv[src]*dinv[dst]} grouped by dst
__global__ void fill_kernel(const int* __restrict__ ei, const int* __restrict__ flag,
                            const float* __restrict__ dinv, int* __restrict__ cursor,
                            int2* __restrict__ csre) {
    int e = blockIdx.x * blockDim.x + threadIdx.x;
    if (e >= N_EDGES) return;
    int s, d;
    if (*flag) { s = ei[2 * e]; d = ei[2 * (N_EDGES + e)]; }
    else       { s = ei[e];     d = ei[N_EDGES + e]; }
    float w = dinv[s] * dinv[d];
    int pos = atomicAdd(&cursor[d], 1);
    int2 r; r.x = s; r.y = __float_as_int(w);
    csre[pos] = r;
}

// Fused MLP stem: h = relu(bn(x@W1^T + b1)); z = h@W2^T + b2.
// Writes A = z and hidden = temp[0]*z.
__launch_bounds__(256)
__global__ void stem_kernel(const float* __restrict__ x, const float* __restrict__ W1,
                            const float* __restrict__ b1, const float* __restrict__ W2,
                            const float* __restrict__ b2, const float* __restrict__ gamma,
                            const float* __restrict__ beta, const float* __restrict__ mean,
                            const float* __restrict__ var, const float* __restrict__ temp,
                            float* __restrict__ A, float* __restrict__ hidden) {
    __shared__ float4 xs4[16 * 125];      // 32 KB: full x tile [16][500]
    __shared__ float  wts[125 * 65];      // 32.5 KB: W1 chunk transposed, padded
    __shared__ float  hs[16 * 65];        // 4.2 KB
    __shared__ float  w2s[40 * 65];       // 10.4 KB

    const float* xs = (const float*)xs4;
    int t = threadIdx.x;
    int node0 = blockIdx.x * 16;

    const float4* xg = (const float4*)(x + (long long)node0 * IN_CH);
    for (int i = t; i < 16 * 125; i += 256) xs4[i] = xg[i];
    for (int i = t; i < OUT_CH * HID; i += 256) {
        int o = i >> 6, hh = i & 63;
        w2s[o * 65 + hh] = W2[i];
    }

    int h = t & 63, grp = t >> 6;
    float acc0 = 0.f, acc1 = 0.f, acc2 = 0.f, acc3 = 0.f;

    for (int kc = 0; kc < 4; ++kc) {
        __syncthreads();
        for (int i = t; i < HID * 125; i += 256) {
            int hh = i / 125, kk = i - hh * 125;
            wts[kk * 65 + hh] = W1[hh * IN_CH + kc * 125 + kk];
        }
        __syncthreads();
        const float* xr0 = xs + (grp * 4 + 0) * IN_CH + kc * 125;
        const float* xr1 = xs + (grp * 4 + 1) * IN_CH + kc * 125;
        const float* xr2 = xs + (grp * 4 + 2) * IN_CH + kc * 125;
        const float* xr3 = xs + (grp * 4 + 3) * IN_CH + kc * 125;
        #pragma unroll 5
        for (int kk = 0; kk < 125; ++kk) {
            float wv = wts[kk * 65 + h];
            acc0 = fmaf(xr0[kk], wv, acc0);
            acc1 = fmaf(xr1[kk], wv, acc1);
            acc2 = fmaf(xr2[kk], wv, acc2);
            acc3 = fmaf(xr3[kk], wv, acc3);
        }
    }

    float sc  = rsqrtf(var[h] + BN_EPS) * gamma[h];
    float off = beta[h] - mean[h] * sc;
    float b1h = b1[h];
    hs[(grp * 4 + 0) * 65 + h] = fmaxf((acc0 + b1h) * sc + off, 0.f);
    hs[(grp * 4 + 1) * 65 + h] = fmaxf((acc1 + b1h) * sc + off, 0.f);
    hs[(grp * 4 + 2) * 65 + h] = fmaxf((acc2 + b1h) * sc + off, 0.f);
    hs[(grp * 4 + 3) * 65 + h] = fmaxf((acc3 + b1h) * sc + off, 0.f);
    __syncthreads();

    float t0 = temp[0];
    for (int idx = t; idx < 16 * OUT_CH; idx += 256) {
        int n = idx / OUT_CH, o = idx - n * OUT_CH;
        const float* hr = hs + n * 65;
        const float* wr = w2s + o * 65;
        float zv = b2[o];
        #pragma unroll 8
        for (int hh = 0; hh < HID; ++hh) zv = fmaf(hr[hh], wr[hh], zv);
        int g = node0 + n;
        A[(long long)g * OUT_CH + o] = zv;
        hidden[(long long)g * OUT_CH + o] = t0 * zv;
    }
}

// One hop: per (node, float4-group) thread gathers over CSR row, no atomics.
// nxt[n] = dinv[n]^2*cur[n] + sum_e w_e * cur[src_e]; hidden += temp[k]*nxt[n].
__launch_bounds__(256)
__global__ void gather_kernel(const int* __restrict__ rowptr, const int2* __restrict__ csre,
                              const float* __restrict__ cur, float* __restrict__ nxt,
                              float* __restrict__ hidden, const float* __restrict__ dinv,
                              const float* __restrict__ temp, int k) {
    int t = blockIdx.x * blockDim.x + threadIdx.x;
    if (t >= N_NODES * 10) return;
    int n = t / 10;                     // lanes g=0..9 of a node are adjacent
    int beg = rowptr[n], end = rowptr[n + 1];
    const float4* curv = (const float4*)cur;
    float dv = dinv[n];
    float d2 = dv * dv;
    float4 c0 = curv[t];
    float4 acc;
    acc.x = d2 * c0.x; acc.y = d2 * c0.y; acc.z = d2 * c0.z; acc.w = d2 * c0.w;
    int g = t - n * 10;
    for (int e = beg; e < end; ++e) {
        int2 r = csre[e];               // broadcast across the node's 10 lanes
        float w = __int_as_float(r.y);
        float4 v = curv[r.x * 10 + g];  // 160B coalesced across the 10 lanes
        acc.x = fmaf(w, v.x, acc.x);
        acc.y = fmaf(w, v.y, acc.y);
        acc.z = fmaf(w, v.z, acc.z);
        acc.w = fmaf(w, v.w, acc.w);
    }
    ((float4*)nxt)[t] = acc;
    float tk = temp[k];
    float4* hp = (float4*)hidden;
    float4 hv = hp[t];
    hv.x = fmaf(tk, acc.x, hv.x);
    hv.y = fmaf(tk, acc.y, hv.y);
    hv.z = fmaf(tk, acc.z, hv.z);
    hv.w = fmaf(tk, acc.w, hv.w);
    hp[t] = hv;
}

// In-place log_softmax over the 40-channel rows of d_out.
__launch_bounds__(256)
__global__ void lsm_kernel(float* __restrict__ out) {
    int n = blockIdx.x * blockDim.x + threadIdx.x;
    if (n >= N_NODES) return;
    float4* p = (float4*)(out + (long long)n * OUT_CH);
    float4 v[10];
    float mx = -INFINITY;
    #pragma unroll
    for (int i = 0; i < 10; ++i) {
        v[i] = p[i];
        mx = fmaxf(mx, fmaxf(fmaxf(v[i].x, v[i].y), fmaxf(v[i].z, v[i].w)));
    }
    float sum = 0.f;
    #pragma unroll
    for (int i = 0; i < 10; ++i) {
        sum += expf(v[i].x - mx) + expf(v[i].y - mx) + expf(v[i].z - mx) + expf(v[i].w - mx);
    }
    float l = mx + logf(sum);
    #pragma unroll
    for (int i = 0; i < 10; ++i) {
        v[i].x -= l; v[i].y -= l; v[i].z -= l; v[i].w -= l;
        p[i] = v[i];
    }
}

extern "C" void kernel_launch(void* const* d_in, const int* in_sizes, int n_in,
                              void* d_out, int out_size, void* d_ws, size_t ws_size,
                              hipStream_t stream) {
    const float* x     = (const float*)d_in[0];
    const int*   ei    = (const int*)d_in[1];
    const float* W1    = (const float*)d_in[2];
    const float* b1    = (const float*)d_in[3];
    const float* W2    = (const float*)d_in[4];
    const float* b2    = (const float*)d_in[5];
    const float* gamma = (const float*)d_in[6];
    const float* beta  = (const float*)d_in[7];
    const float* mean  = (const float*)d_in[8];
    const float* var   = (const float*)d_in[9];
    const float* temp  = (const float*)d_in[10];
    float* out = (float*)d_out;

    char* ws = (char*)d_ws;
    int*   flag   = (int*)(ws + OFF_FLAG);
    int*   deg    = (int*)(ws + OFF_DEG);
    int*   rowptr = (int*)(ws + OFF_ROWPTR);
    int*   cursor = (int*)(ws + OFF_CURSOR);
    float* dinv   = (float*)(ws + OFF_DINV);
    int*   bsum   = (int*)(ws + OFF_BSUM);
    int*   bscan  = (int*)(ws + OFF_BSCAN);
    int2*  csre   = (int2*)(ws + OFF_CSRE);
    float* A      = (float*)(ws + OFF_A);
    float* B      = (float*)(ws + OFF_B);

    int gridE = (N_EDGES + 255) / 256;
    int gridN = (N_NODES + 255) / 256;

    detect_kernel<<<1, 64, 0, stream>>>((const unsigned int*)ei, flag);
    zero_deg_kernel<<<gridN, 256, 0, stream>>>(deg);
    deg_kernel<<<gridE, 256, 0, stream>>>(ei, flag, deg);
    scan_reduce_kernel<<<NB_SCAN, 256, 0, stream>>>(deg, bsum);
    scan_bsums_kernel<<<1, 512, 0, stream>>>(bsum, bscan);
    scan_final_kernel<<<NB_SCAN, 256, 0, stream>>>(deg, bscan, rowptr);
    finalize_kernel<<<gridN, 256, 0, stream>>>(deg, rowptr, dinv, cursor);
    fill_kernel<<<gridE, 256, 0, stream>>>(ei, flag, dinv, cursor, csre);

    stem_kernel<<<N_NODES / 16, 256, 0, stream>>>(x, W1, b1, W2, b2, gamma, beta,
                                                  mean, var, temp, A, out);

    float* cur = A;
    float* nxt = B;
    for (int k = 0; k < K_HOPS; ++k) {
        gather_kernel<<<(N_NODES * 10 + 255) / 256, 256, 0, stream>>>(
            rowptr, csre, cur, nxt, out, dinv, temp, k + 1);
        float* t2 = cur; cur = nxt; nxt = t2;
    }

    lsm_kernel<<<gridN, 256, 0, stream>>>(out);
}

// Round 3
// 1707.824 us; speedup vs baseline: 24.4493x; 1.2307x over previous
//
#include <hip/hip_runtime.h>
#include <math.h>

#define N_NODES 100000
#define N_EDGES 3200000
#define IN_CH   500
#define HID     64
#define OUT_CH  40
#define K_HOPS  10
#define BN_EPS  1e-5f
#define NB_SCAN ((N_NODES + 255) / 256)   // 391

// ---------------- workspace layout (bytes) ----------------
#define OFF_FLAG    0           // 512
#define OFF_DEG     512         // N*4
#define OFF_ROWPTR  400896      // (N+1)*4
#define OFF_CURSOR  801024      // N*4
#define OFF_DINV    1201024     // N*4
#define OFF_BSUM    1601024     // 2048
#define OFF_BSCAN   1603072     // 2048
#define OFF_CSRE    1605632     // E*8 = 25.6MB (int2 {src, w})
#define OFF_A       27205632    // N*40*4 = 16MB
#define OFF_B       43205632    // 16MB

using bf16x8 = __attribute__((ext_vector_type(8))) short;
using f32x4  = __attribute__((ext_vector_type(4))) float;

__device__ inline short f2bf(float f) {
    unsigned u = __float_as_uint(f);
    return (short)((u + 0x7FFFu + ((u >> 16) & 1u)) >> 16);   // RNE
}

// Detect int64 vs int32 edge_index storage (odd 32-bit words all zero <=> int64).
__global__ void detect_kernel(const unsigned int* __restrict__ ei, int* __restrict__ flag) {
    if (blockIdx.x == 0 && threadIdx.x == 0) {
        int is64 = 1;
        for (int i = 1; i < 64; i += 2) {
            if (ei[i] != 0u) { is64 = 0; break; }
        }
        *flag = is64;
    }
}

__global__ void zero_deg_kernel(int* __restrict__ deg) {
    int i = blockIdx.x * blockDim.x + threadIdx.x;
    if (i < N_NODES) deg[i] = 0;
}

__global__ void deg_kernel(const int* __restrict__ ei, const int* __restrict__ flag,
                           int* __restrict__ deg) {
    int e = blockIdx.x * blockDim.x + threadIdx.x;
    if (e >= N_EDGES) return;
    int d = (*flag) ? ei[2 * (N_EDGES + e)] : ei[N_EDGES + e];
    atomicAdd(&deg[d], 1);
}

// 3-kernel exclusive prefix scan of deg -> rowptr
__global__ void scan_reduce_kernel(const int* __restrict__ deg, int* __restrict__ bsum) {
    __shared__ int s[256];
    int i = blockIdx.x * 256 + threadIdx.x;
    s[threadIdx.x] = (i < N_NODES) ? deg[i] : 0;
    __syncthreads();
    for (int off = 128; off > 0; off >>= 1) {
        if (threadIdx.x < off) s[threadIdx.x] += s[threadIdx.x + off];
        __syncthreads();
    }
    if (threadIdx.x == 0) bsum[blockIdx.x] = s[0];
}

__global__ void scan_bsums_kernel(const int* __restrict__ bsum, int* __restrict__ bscan) {
    __shared__ int s[512];
    int t = threadIdx.x;
    int orig = (t < NB_SCAN) ? bsum[t] : 0;
    s[t] = orig;
    __syncthreads();
    for (int off = 1; off < 512; off <<= 1) {
        int v = (t >= off) ? s[t - off] : 0;
        __syncthreads();
        s[t] += v;
        __syncthreads();
    }
    if (t < NB_SCAN) bscan[t] = s[t] - orig;   // exclusive
}

__global__ void scan_final_kernel(const int* __restrict__ deg, const int* __restrict__ bscan,
                                  int* __restrict__ rowptr) {
    __shared__ int s[256];
    int i = blockIdx.x * 256 + threadIdx.x;
    int v = (i < N_NODES) ? deg[i] : 0;
    s[threadIdx.x] = v;
    __syncthreads();
    for (int off = 1; off < 256; off <<= 1) {
        int u = (threadIdx.x >= off) ? s[threadIdx.x - off] : 0;
        __syncthreads();
        s[threadIdx.x] += u;
        __syncthreads();
    }
    if (i < N_NODES) rowptr[i] = bscan[blockIdx.x] + s[threadIdx.x] - v;
    if (i == N_NODES - 1) rowptr[N_NODES] = bscan[blockIdx.x] + s[threadIdx.x];
}

__global__ void finalize_kernel(const int* __restrict__ deg, const int* __restrict__ rowptr,
                                float* __restrict__ dinv, int* __restrict__ cursor) {
    int i = blockIdx.x * blockDim.x + threadIdx.x;
    if (i >= N_NODES) return;
    dinv[i] = rsqrtf((float)deg[i] + 1.0f);
    cursor[i] = rowptr[i];
}

__global__ void fill_kernel(const int* __restrict__ ei, const int* __restrict__ flag,
                            const float* __restrict__ dinv, int* __restrict__ cursor,
                            int2* __restrict__ csre) {
    int e = blockIdx.x * blockDim.x + threadIdx.x;
    if (e >= N_EDGES) return;
    int s, d;
    if (*flag) { s = ei[2 * e]; d = ei[2 * (N_EDGES + e)]; }
    else       { s = ei[e];     d = ei[N_EDGES + e]; }
    float w = dinv[s] * dinv[d];
    int pos = atomicAdd(&cursor[d], 1);
    int2 r; r.x = s; r.y = __float_as_int(w);
    csre[pos] = r;
}

// MFMA MLP stem: z = relu(bn(x@W1^T+b1))@W2^T + b2. 128 nodes/block, 4 waves.
// bf16 inputs converted on the fly, fp32 accumulate. Writes A=z, hidden=temp[0]*z.
__launch_bounds__(256, 2)
__global__ void stem_kernel(const float* __restrict__ x, const float* __restrict__ W1,
                            const float* __restrict__ b1, const float* __restrict__ W2,
                            const float* __restrict__ b2, const float* __restrict__ gamma,
                            const float* __restrict__ beta, const float* __restrict__ mean,
                            const float* __restrict__ var, const float* __restrict__ temp,
                            float* __restrict__ A, float* __restrict__ hidden) {
    // phase1: xs = x chunk bf16 [128][72], wls = W1 chunk bf16 [64][72]
    // phase2: xs = h bf16 [128][72],       wls = W2 bf16 [48][72] (rows 40..47 zero)
    alignas(16) __shared__ short xs[128 * 72];
    alignas(16) __shared__ short wls[64 * 72];

    const int t    = threadIdx.x;
    const int lane = t & 63;
    const int w    = t >> 6;        // wave 0..3 -> rows w*32..w*32+31
    const int ln   = lane & 15;     // fragment row/col index
    const int kg   = lane >> 4;     // k-group 0..3
    const int n0   = blockIdx.x * 128;
    const int r16  = t >> 4;        // 0..15
    const int c4   = t & 15;        // float4 column

    f32x4 acc[2][4];
    #pragma unroll
    for (int mt = 0; mt < 2; ++mt)
        #pragma unroll
        for (int nt = 0; nt < 4; ++nt) {
            f32x4 z = {0.f, 0.f, 0.f, 0.f};
            acc[mt][nt] = z;
        }

    for (int kc = 0; kc < 8; ++kc) {
        __syncthreads();
        int kb = kc * 64 + c4 * 4;
        bool inb = (kb + 4 <= IN_CH);
        // stage x chunk: 8 iters x 16 rows, coalesced float4, convert to bf16
        #pragma unroll
        for (int it = 0; it < 8; ++it) {
            int r = it * 16 + r16;
            long long gr = n0 + r;
            if (gr >= N_NODES) gr = N_NODES - 1;
            float4 v = inb ? *(const float4*)(x + gr * IN_CH + kb)
                           : make_float4(0.f, 0.f, 0.f, 0.f);
            short4 s4; s4.x = f2bf(v.x); s4.y = f2bf(v.y); s4.z = f2bf(v.z); s4.w = f2bf(v.w);
            *(short4*)&xs[r * 72 + c4 * 4] = s4;
        }
        // stage W1 chunk: 4 iters x 16 rows
        #pragma unroll
        for (int it = 0; it < 4; ++it) {
            int r = it * 16 + r16;
            float4 v = inb ? *(const float4*)(W1 + r * IN_CH + kb)
                           : make_float4(0.f, 0.f, 0.f, 0.f);
            short4 s4; s4.x = f2bf(v.x); s4.y = f2bf(v.y); s4.z = f2bf(v.z); s4.w = f2bf(v.w);
            *(short4*)&wls[r * 72 + c4 * 4] = s4;
        }
        __syncthreads();

        bf16x8 af[2][2], bfr[4][2];
        #pragma unroll
        for (int mt = 0; mt < 2; ++mt)
            #pragma unroll
            for (int ks = 0; ks < 2; ++ks)
                af[mt][ks] = *(const bf16x8*)&xs[(w * 32 + mt * 16 + ln) * 72 + ks * 32 + kg * 8];
        #pragma unroll
        for (int nt = 0; nt < 4; ++nt)
            #pragma unroll
            for (int ks = 0; ks < 2; ++ks)
                bfr[nt][ks] = *(const bf16x8*)&wls[(nt * 16 + ln) * 72 + ks * 32 + kg * 8];
        #pragma unroll
        for (int mt = 0; mt < 2; ++mt)
            #pragma unroll
            for (int nt = 0; nt < 4; ++nt)
                #pragma unroll
                for (int ks = 0; ks < 2; ++ks)
                    acc[mt][nt] = __builtin_amdgcn_mfma_f32_16x16x32_bf16(
                        af[mt][ks], bfr[nt][ks], acc[mt][nt], 0, 0, 0);
    }
    __syncthreads();

    // BN + ReLU in registers; h -> xs (bf16). C/D layout: col=lane&15, row=(lane>>4)*4+j.
    float sc[4], of[4];
    #pragma unroll
    for (int nt = 0; nt < 4; ++nt) {
        int c = nt * 16 + ln;
        float s_ = rsqrtf(var[c] + BN_EPS) * gamma[c];
        sc[nt] = s_;
        of[nt] = (b1[c] - mean[c]) * s_ + beta[c];
    }
    #pragma unroll
    for (int mt = 0; mt < 2; ++mt)
        #pragma unroll
        for (int nt = 0; nt < 4; ++nt)
            #pragma unroll
            for (int j = 0; j < 4; ++j) {
                int row = w * 32 + mt * 16 + kg * 4 + j;
                float h = fmaxf(acc[mt][nt][j] * sc[nt] + of[nt], 0.f);
                xs[row * 72 + nt * 16 + ln] = f2bf(h);
            }
    // stage W2 -> wls (rows 0..39), zero rows 40..47
    for (int i = t; i < 40 * 16; i += 256) {
        int r = i >> 4, cc = i & 15;
        float4 v = *(const float4*)(W2 + r * HID + cc * 4);
        short4 s4; s4.x = f2bf(v.x); s4.y = f2bf(v.y); s4.z = f2bf(v.z); s4.w = f2bf(v.w);
        *(short4*)&wls[r * 72 + cc * 4] = s4;
    }
    for (int i = t; i < 8 * 16; i += 256) {
        int r = 40 + (i >> 4), cc = i & 15;
        short4 z4 = {0, 0, 0, 0};
        *(short4*)&wls[r * 72 + cc * 4] = z4;
    }
    __syncthreads();

    // GEMM2: z[128][40] = h[128][64] @ W2^T (N padded to 48)
    f32x4 acc2[2][3];
    #pragma unroll
    for (int mt = 0; mt < 2; ++mt)
        #pragma unroll
        for (int nt = 0; nt < 3; ++nt) {
            f32x4 z = {0.f, 0.f, 0.f, 0.f};
            acc2[mt][nt] = z;
        }
    bf16x8 a2[2][2], b2f[3][2];
    #pragma unroll
    for (int mt = 0; mt < 2; ++mt)
        #pragma unroll
        for (int ks = 0; ks < 2; ++ks)
            a2[mt][ks] = *(const bf16x8*)&xs[(w * 32 + mt * 16 + ln) * 72 + ks * 32 + kg * 8];
    #pragma unroll
    for (int nt = 0; nt < 3; ++nt)
        #pragma unroll
        for (int ks = 0; ks < 2; ++ks)
            b2f[nt][ks] = *(const bf16x8*)&wls[(nt * 16 + ln) * 72 + ks * 32 + kg * 8];
    #pragma unroll
    for (int mt = 0; mt < 2; ++mt)
        #pragma unroll
        for (int nt = 0; nt < 3; ++nt)
            #pragma unroll
            for (int ks = 0; ks < 2; ++ks)
                acc2[mt][nt] = __builtin_amdgcn_mfma_f32_16x16x32_bf16(
                    a2[mt][ks], b2f[nt][ks], acc2[mt][nt], 0, 0, 0);

    float t0 = temp[0];
    float bb[3];
    #pragma unroll
    for (int nt = 0; nt < 3; ++nt) {
        int c = nt * 16 + ln;
        bb[nt] = (c < OUT_CH) ? b2[c] : 0.f;
    }
    #pragma unroll
    for (int mt = 0; mt < 2; ++mt)
        #pragma unroll
        for (int nt = 0; nt < 3; ++nt) {
            int c = nt * 16 + ln;
            if (c >= OUT_CH) continue;
            #pragma unroll
            for (int j = 0; j < 4; ++j) {
                int row = w * 32 + mt * 16 + kg * 4 + j;
                long long g = n0 + row;
                if (g < N_NODES) {
                    float z = acc2[mt][nt][j] + bb[nt];
                    A[g * OUT_CH + c] = z;
                    hidden[g * OUT_CH + c] = t0 * z;
                }
            }
        }
}

// One hop: per (node, float4-group) thread gathers over CSR row, no atomics.
// Unroll-by-4 keeps 4 independent csre->curv chains in flight.
__launch_bounds__(256)
__global__ void gather_kernel(const int* __restrict__ rowptr, const int2* __restrict__ csre,
                              const float* __restrict__ cur, float* __restrict__ nxt,
                              float* __restrict__ hidden, const float* __restrict__ dinv,
                              const float* __restrict__ temp, int k) {
    int t = blockIdx.x * blockDim.x + threadIdx.x;
    if (t >= N_NODES * 10) return;
    int n = t / 10;
    int g = t - n * 10;
    int beg = rowptr[n], end = rowptr[n + 1];
    const float4* curv = (const float4*)cur;
    float dv = dinv[n];
    float d2 = dv * dv;
    float4 c0 = curv[t];
    float4 acc;
    acc.x = d2 * c0.x; acc.y = d2 * c0.y; acc.z = d2 * c0.z; acc.w = d2 * c0.w;

    int e = beg;
    for (; e + 4 <= end; e += 4) {
        int2 r0 = csre[e + 0], r1 = csre[e + 1], r2 = csre[e + 2], r3 = csre[e + 3];
        float4 v0 = curv[r0.x * 10 + g];
        float4 v1 = curv[r1.x * 10 + g];
        float4 v2 = curv[r2.x * 10 + g];
        float4 v3 = curv[r3.x * 10 + g];
        float w0 = __int_as_float(r0.y), w1 = __int_as_float(r1.y);
        float w2 = __int_as_float(r2.y), w3 = __int_as_float(r3.y);
        acc.x = fmaf(w0, v0.x, acc.x); acc.y = fmaf(w0, v0.y, acc.y);
        acc.z = fmaf(w0, v0.z, acc.z); acc.w = fmaf(w0, v0.w, acc.w);
        acc.x = fmaf(w1, v1.x, acc.x); acc.y = fmaf(w1, v1.y, acc.y);
        acc.z = fmaf(w1, v1.z, acc.z); acc.w = fmaf(w1, v1.w, acc.w);
        acc.x = fmaf(w2, v2.x, acc.x); acc.y = fmaf(w2, v2.y, acc.y);
        acc.z = fmaf(w2, v2.z, acc.z); acc.w = fmaf(w2, v2.w, acc.w);
        acc.x = fmaf(w3, v3.x, acc.x); acc.y = fmaf(w3, v3.y, acc.y);
        acc.z = fmaf(w3, v3.z, acc.z); acc.w = fmaf(w3, v3.w, acc.w);
    }
    for (; e < end; ++e) {
        int2 r = csre[e];
        float w = __int_as_float(r.y);
        float4 v = curv[r.x * 10 + g];
        acc.x = fmaf(w, v.x, acc.x); acc.y = fmaf(w, v.y, acc.y);
        acc.z = fmaf(w, v.z, acc.z); acc.w = fmaf(w, v.w, acc.w);
    }

    ((float4*)nxt)[t] = acc;
    float tk = temp[k];
    float4* hp = (float4*)hidden;
    float4 hv = hp[t];
    hv.x = fmaf(tk, acc.x, hv.x);
    hv.y = fmaf(tk, acc.y, hv.y);
    hv.z = fmaf(tk, acc.z, hv.z);
    hv.w = fmaf(tk, acc.w, hv.w);
    hp[t] = hv;
}

// In-place log_softmax over the 40-channel rows of d_out.
__launch_bounds__(256)
__global__ void lsm_kernel(float* __restrict__ out) {
    int n = blockIdx.x * blockDim.x + threadIdx.x;
    if (n >= N_NODES) return;
    float4* p = (float4*)(out + (long long)n * OUT_CH);
    float4 v[10];
    float mx = -INFINITY;
    #pragma unroll
    for (int i = 0; i < 10; ++i) {
        v[i] = p[i];
        mx = fmaxf(mx, fmaxf(fmaxf(v[i].x, v[i].y), fmaxf(v[i].z, v[i].w)));
    }
    float sum = 0.f;
    #pragma unroll
    for (int i = 0; i < 10; ++i) {
        sum += expf(v[i].x - mx) + expf(v[i].y - mx) + expf(v[i].z - mx) + expf(v[i].w - mx);
    }
    float l = mx + logf(sum);
    #pragma unroll
    for (int i = 0; i < 10; ++i) {
        v[i].x -= l; v[i].y -= l; v[i].z -= l; v[i].w -= l;
        p[i] = v[i];
    }
}

extern "C" void kernel_launch(void* const* d_in, const int* in_sizes, int n_in,
                              void* d_out, int out_size, void* d_ws, size_t ws_size,
                              hipStream_t stream) {
    const float* x     = (const float*)d_in[0];
    const int*   ei    = (const int*)d_in[1];
    const float* W1    = (const float*)d_in[2];
    const float* b1    = (const float*)d_in[3];
    const float* W2    = (const float*)d_in[4];
    const float* b2    = (const float*)d_in[5];
    const float* gamma = (const float*)d_in[6];
    const float* beta  = (const float*)d_in[7];
    const float* mean  = (const float*)d_in[8];
    const float* var   = (const float*)d_in[9];
    const float* temp  = (const float*)d_in[10];
    float* out = (float*)d_out;

    char* ws = (char*)d_ws;
    int*   flag   = (int*)(ws + OFF_FLAG);
    int*   deg    = (int*)(ws + OFF_DEG);
    int*   rowptr = (int*)(ws + OFF_ROWPTR);
    int*   cursor = (int*)(ws + OFF_CURSOR);
    float* dinv   = (float*)(ws + OFF_DINV);
    int*   bsum   = (int*)(ws + OFF_BSUM);
    int*   bscan  = (int*)(ws + OFF_BSCAN);
    int2*  csre   = (int2*)(ws + OFF_CSRE);
    float* A      = (float*)(ws + OFF_A);
    float* B      = (float*)(ws + OFF_B);

    int gridE = (N_EDGES + 255) / 256;
    int gridN = (N_NODES + 255) / 256;

    detect_kernel<<<1, 64, 0, stream>>>((const unsigned int*)ei, flag);
    zero_deg_kernel<<<gridN, 256, 0, stream>>>(deg);
    deg_kernel<<<gridE, 256, 0, stream>>>(ei, flag, deg);
    scan_reduce_kernel<<<NB_SCAN, 256, 0, stream>>>(deg, bsum);
    scan_bsums_kernel<<<1, 512, 0, stream>>>(bsum, bscan);
    scan_final_kernel<<<NB_SCAN, 256, 0, stream>>>(deg, bscan, rowptr);
    finalize_kernel<<<gridN, 256, 0, stream>>>(deg, rowptr, dinv, cursor);
    fill_kernel<<<gridE, 256, 0, stream>>>(ei, flag, dinv, cursor, csre);

    stem_kernel<<<(N_NODES + 127) / 128, 256, 0, stream>>>(x, W1, b1, W2, b2, gamma, beta,
                                                           mean, var, temp, A, out);

    float* cur = A;
    float* nxt = B;
    for (int k = 0; k < K_HOPS; ++k) {
        gather_kernel<<<(N_NODES * 10 + 255) / 256, 256, 0, stream>>>(
            rowptr, csre, cur, nxt, out, dinv, temp, k + 1);
        float* t2 = cur; cur = nxt; nxt = t2;
    }

    lsm_kernel<<<gridN, 256, 0, stream>>>(out);
}

// Round 4
// 1288.949 us; speedup vs baseline: 32.3947x; 1.3250x over previous
//
#include <hip/hip_runtime.h>
#include <math.h>

#define N_NODES 100000
#define N_EDGES 3200000
#define IN_CH   500
#define HID     64
#define OUT_CH  40
#define K_HOPS  10
#define BN_EPS  1e-5f
#define NB_SCAN ((N_NODES + 255) / 256)   // 391

// ---------------- workspace layout (bytes) ----------------
#define OFF_FLAG    0           // 512
#define OFF_DEG     512         // N*4           -> 400512
#define OFF_ROWPTR  400896      // (N+1)*4       -> 800900
#define OFF_DINV    801024      // N*4           -> 1201024
#define OFF_BSUM    1201024     // 2048
#define OFF_BSCAN   1203072     // 2048
#define OFF_RANK    1205248     // E*4 = 12.8MB  -> 14005248
#define OFF_CSRE    14005248    // E*8 = 25.6MB  -> 39605248  (int2 {src, w})
#define OFF_CURB    39605248    // N*40*2 = 8MB  -> 47605248  (bf16 state)
#define OFF_NXTB    47605248    // 8MB           -> 55605248

using bf16x8 = __attribute__((ext_vector_type(8))) short;
using f32x4  = __attribute__((ext_vector_type(4))) float;

__device__ inline short f2bf(float f) {
    unsigned u = __float_as_uint(f);
    return (short)((u + 0x7FFFu + ((u >> 16) & 1u)) >> 16);   // RNE
}
__device__ inline unsigned pack2bf(float lo, float hi) {
    return (unsigned)(unsigned short)f2bf(lo) | ((unsigned)(unsigned short)f2bf(hi) << 16);
}
__device__ inline float bflo(unsigned u) { return __uint_as_float(u << 16); }
__device__ inline float bfhi(unsigned u) { return __uint_as_float(u & 0xFFFF0000u); }

// Detect int64 vs int32 edge_index storage (odd 32-bit words all zero <=> int64).
__global__ void detect_kernel(const unsigned int* __restrict__ ei, int* __restrict__ flag) {
    if (blockIdx.x == 0 && threadIdx.x == 0) {
        int is64 = 1;
        for (int i = 1; i < 64; i += 2) {
            if (ei[i] != 0u) { is64 = 0; break; }
        }
        *flag = is64;
    }
}

__global__ void zero_deg_kernel(int* __restrict__ deg) {
    int i = blockIdx.x * blockDim.x + threadIdx.x;
    if (i < N_NODES) deg[i] = 0;
}

// Count degree AND record each edge's rank among its dst's edges (one atomic pass).
__global__ void deg_rank_kernel(const int* __restrict__ ei, const int* __restrict__ flag,
                                int* __restrict__ deg, int* __restrict__ rank) {
    int e = blockIdx.x * blockDim.x + threadIdx.x;
    if (e >= N_EDGES) return;
    int d = (*flag) ? ei[2 * (N_EDGES + e)] : ei[N_EDGES + e];
    rank[e] = atomicAdd(&deg[d], 1);
}

// 3-kernel exclusive prefix scan of deg -> rowptr
__global__ void scan_reduce_kernel(const int* __restrict__ deg, int* __restrict__ bsum) {
    __shared__ int s[256];
    int i = blockIdx.x * 256 + threadIdx.x;
    s[threadIdx.x] = (i < N_NODES) ? deg[i] : 0;
    __syncthreads();
    for (int off = 128; off > 0; off >>= 1) {
        if (threadIdx.x < off) s[threadIdx.x] += s[threadIdx.x + off];
        __syncthreads();
    }
    if (threadIdx.x == 0) bsum[blockIdx.x] = s[0];
}

__global__ void scan_bsums_kernel(const int* __restrict__ bsum, int* __restrict__ bscan) {
    __shared__ int s[512];
    int t = threadIdx.x;
    int orig = (t < NB_SCAN) ? bsum[t] : 0;
    s[t] = orig;
    __syncthreads();
    for (int off = 1; off < 512; off <<= 1) {
        int v = (t >= off) ? s[t - off] : 0;
        __syncthreads();
        s[t] += v;
        __syncthreads();
    }
    if (t < NB_SCAN) bscan[t] = s[t] - orig;   // exclusive
}

__global__ void scan_final_kernel(const int* __restrict__ deg, const int* __restrict__ bscan,
                                  int* __restrict__ rowptr) {
    __shared__ int s[256];
    int i = blockIdx.x * 256 + threadIdx.x;
    int v = (i < N_NODES) ? deg[i] : 0;
    s[threadIdx.x] = v;
    __syncthreads();
    for (int off = 1; off < 256; off <<= 1) {
        int u = (threadIdx.x >= off) ? s[threadIdx.x - off] : 0;
        __syncthreads();
        s[threadIdx.x] += u;
        __syncthreads();
    }
    if (i < N_NODES) rowptr[i] = bscan[blockIdx.x] + s[threadIdx.x] - v;
    if (i == N_NODES - 1) rowptr[N_NODES] = bscan[blockIdx.x] + s[threadIdx.x];
}

__global__ void finalize_kernel(const int* __restrict__ deg, float* __restrict__ dinv) {
    int i = blockIdx.x * blockDim.x + threadIdx.x;
    if (i >= N_NODES) return;
    dinv[i] = rsqrtf((float)deg[i] + 1.0f);
}

// Atomic-free CSR fill: pos = rowptr[d] + rank[e].
__global__ void fill_kernel(const int* __restrict__ ei, const int* __restrict__ flag,
                            const float* __restrict__ dinv, const int* __restrict__ rowptr,
                            const int* __restrict__ rank, int2* __restrict__ csre) {
    int e = blockIdx.x * blockDim.x + threadIdx.x;
    if (e >= N_EDGES) return;
    int s, d;
    if (*flag) { s = ei[2 * e]; d = ei[2 * (N_EDGES + e)]; }
    else       { s = ei[e];     d = ei[N_EDGES + e]; }
    float w = dinv[s] * dinv[d];
    int pos = rowptr[d] + rank[e];
    int2 r; r.x = s; r.y = __float_as_int(w);
    csre[pos] = r;
}

// MFMA MLP stem: z = relu(bn(x@W1^T+b1))@W2^T + b2. 128 nodes/block, 4 waves.
// Writes curb = bf16(z), hidden = temp[0]*z (fp32).
__launch_bounds__(256, 2)
__global__ void stem_kernel(const float* __restrict__ x, const float* __restrict__ W1,
                            const float* __restrict__ b1, const float* __restrict__ W2,
                            const float* __restrict__ b2, const float* __restrict__ gamma,
                            const float* __restrict__ beta, const float* __restrict__ mean,
                            const float* __restrict__ var, const float* __restrict__ temp,
                            unsigned short* __restrict__ curb, float* __restrict__ hidden) {
    alignas(16) __shared__ short xs[128 * 72];
    alignas(16) __shared__ short wls[64 * 72];

    const int t    = threadIdx.x;
    const int lane = t & 63;
    const int w    = t >> 6;
    const int ln   = lane & 15;
    const int kg   = lane >> 4;
    const int n0   = blockIdx.x * 128;
    const int r16  = t >> 4;
    const int c4   = t & 15;

    f32x4 acc[2][4];
    #pragma unroll
    for (int mt = 0; mt < 2; ++mt)
        #pragma unroll
        for (int nt = 0; nt < 4; ++nt) {
            f32x4 z = {0.f, 0.f, 0.f, 0.f};
            acc[mt][nt] = z;
        }

    for (int kc = 0; kc < 8; ++kc) {
        __syncthreads();
        int kb = kc * 64 + c4 * 4;
        bool inb = (kb + 4 <= IN_CH);
        #pragma unroll
        for (int it = 0; it < 8; ++it) {
            int r = it * 16 + r16;
            long long gr = n0 + r;
            if (gr >= N_NODES) gr = N_NODES - 1;
            float4 v = inb ? *(const float4*)(x + gr * IN_CH + kb)
                           : make_float4(0.f, 0.f, 0.f, 0.f);
            short4 s4; s4.x = f2bf(v.x); s4.y = f2bf(v.y); s4.z = f2bf(v.z); s4.w = f2bf(v.w);
            *(short4*)&xs[r * 72 + c4 * 4] = s4;
        }
        #pragma unroll
        for (int it = 0; it < 4; ++it) {
            int r = it * 16 + r16;
            float4 v = inb ? *(const float4*)(W1 + r * IN_CH + kb)
                           : make_float4(0.f, 0.f, 0.f, 0.f);
            short4 s4; s4.x = f2bf(v.x); s4.y = f2bf(v.y); s4.z = f2bf(v.z); s4.w = f2bf(v.w);
            *(short4*)&wls[r * 72 + c4 * 4] = s4;
        }
        __syncthreads();

        bf16x8 af[2][2], bfr[4][2];
        #pragma unroll
        for (int mt = 0; mt < 2; ++mt)
            #pragma unroll
            for (int ks = 0; ks < 2; ++ks)
                af[mt][ks] = *(const bf16x8*)&xs[(w * 32 + mt * 16 + ln) * 72 + ks * 32 + kg * 8];
        #pragma unroll
        for (int nt = 0; nt < 4; ++nt)
            #pragma unroll
            for (int ks = 0; ks < 2; ++ks)
                bfr[nt][ks] = *(const bf16x8*)&wls[(nt * 16 + ln) * 72 + ks * 32 + kg * 8];
        #pragma unroll
        for (int mt = 0; mt < 2; ++mt)
            #pragma unroll
            for (int nt = 0; nt < 4; ++nt)
                #pragma unroll
                for (int ks = 0; ks < 2; ++ks)
                    acc[mt][nt] = __builtin_amdgcn_mfma_f32_16x16x32_bf16(
                        af[mt][ks], bfr[nt][ks], acc[mt][nt], 0, 0, 0);
    }
    __syncthreads();

    // BN + ReLU in registers; h -> xs (bf16). C/D layout: col=lane&15, row=(lane>>4)*4+j.
    float sc[4], of[4];
    #pragma unroll
    for (int nt = 0; nt < 4; ++nt) {
        int c = nt * 16 + ln;
        float s_ = rsqrtf(var[c] + BN_EPS) * gamma[c];
        sc[nt] = s_;
        of[nt] = (b1[c] - mean[c]) * s_ + beta[c];
    }
    #pragma unroll
    for (int mt = 0; mt < 2; ++mt)
        #pragma unroll
        for (int nt = 0; nt < 4; ++nt)
            #pragma unroll
            for (int j = 0; j < 4; ++j) {
                int row = w * 32 + mt * 16 + kg * 4 + j;
                float h = fmaxf(acc[mt][nt][j] * sc[nt] + of[nt], 0.f);
                xs[row * 72 + nt * 16 + ln] = f2bf(h);
            }
    for (int i = t; i < 40 * 16; i += 256) {
        int r = i >> 4, cc = i & 15;
        float4 v = *(const float4*)(W2 + r * HID + cc * 4);
        short4 s4; s4.x = f2bf(v.x); s4.y = f2bf(v.y); s4.z = f2bf(v.z); s4.w = f2bf(v.w);
        *(short4*)&wls[r * 72 + cc * 4] = s4;
    }
    for (int i = t; i < 8 * 16; i += 256) {
        int r = 40 + (i >> 4), cc = i & 15;
        short4 z4 = {0, 0, 0, 0};
        *(short4*)&wls[r * 72 + cc * 4] = z4;
    }
    __syncthreads();

    // GEMM2: z[128][40] = h[128][64] @ W2^T (N padded to 48)
    f32x4 acc2[2][3];
    #pragma unroll
    for (int mt = 0; mt < 2; ++mt)
        #pragma unroll
        for (int nt = 0; nt < 3; ++nt) {
            f32x4 z = {0.f, 0.f, 0.f, 0.f};
            acc2[mt][nt] = z;
        }
    bf16x8 a2[2][2], b2f[3][2];
    #pragma unroll
    for (int mt = 0; mt < 2; ++mt)
        #pragma unroll
        for (int ks = 0; ks < 2; ++ks)
            a2[mt][ks] = *(const bf16x8*)&xs[(w * 32 + mt * 16 + ln) * 72 + ks * 32 + kg * 8];
    #pragma unroll
    for (int nt = 0; nt < 3; ++nt)
        #pragma unroll
        for (int ks = 0; ks < 2; ++ks)
            b2f[nt][ks] = *(const bf16x8*)&wls[(nt * 16 + ln) * 72 + ks * 32 + kg * 8];
    #pragma unroll
    for (int mt = 0; mt < 2; ++mt)
        #pragma unroll
        for (int nt = 0; nt < 3; ++nt)
            #pragma unroll
            for (int ks = 0; ks < 2; ++ks)
                acc2[mt][nt] = __builtin_amdgcn_mfma_f32_16x16x32_bf16(
                    a2[mt][ks], b2f[nt][ks], acc2[mt][nt], 0, 0, 0);

    float t0 = temp[0];
    float bb[3];
    #pragma unroll
    for (int nt = 0; nt < 3; ++nt) {
        int c = nt * 16 + ln;
        bb[nt] = (c < OUT_CH) ? b2[c] : 0.f;
    }
    #pragma unroll
    for (int mt = 0; mt < 2; ++mt)
        #pragma unroll
        for (int nt = 0; nt < 3; ++nt) {
            int c = nt * 16 + ln;
            if (c >= OUT_CH) continue;
            #pragma unroll
            for (int j = 0; j < 4; ++j) {
                int row = w * 32 + mt * 16 + kg * 4 + j;
                long long g = n0 + row;
                if (g < N_NODES) {
                    float z = acc2[mt][nt][j] + bb[nt];
                    curb[g * OUT_CH + c] = (unsigned short)f2bf(z);
                    hidden[g * OUT_CH + c] = t0 * z;
                }
            }
        }
}

// One hop, bf16 state: 5 threads/node, each owns 8 channels (16B).
// nxt[n] = bf16(dinv^2*cur[n] + sum_e w_e*cur[src_e]); hidden += temp[k]*(fp32 acc).
__launch_bounds__(256)
__global__ void gather_kernel(const int* __restrict__ rowptr, const int2* __restrict__ csre,
                              const unsigned short* __restrict__ cur,
                              unsigned short* __restrict__ nxt,
                              float* __restrict__ hidden, const float* __restrict__ dinv,
                              const float* __restrict__ temp, int k) {
    int t = blockIdx.x * blockDim.x + threadIdx.x;
    if (t >= N_NODES * 5) return;
    int n = t / 5;
    int g = t - n * 5;
    int beg = rowptr[n], end = rowptr[n + 1];
    const uint4* curv = (const uint4*)cur;     // row n, group g at index n*5+g
    float dv = dinv[n];
    float d2 = dv * dv;
    uint4 sf = curv[t];
    float acc0 = d2 * bflo(sf.x), acc1 = d2 * bfhi(sf.x);
    float acc2 = d2 * bflo(sf.y), acc3 = d2 * bfhi(sf.y);
    float acc4 = d2 * bflo(sf.z), acc5 = d2 * bfhi(sf.z);
    float acc6 = d2 * bflo(sf.w), acc7 = d2 * bfhi(sf.w);

    int e = beg;
    for (; e + 4 <= end; e += 4) {
        int2 r0 = csre[e + 0], r1 = csre[e + 1], r2 = csre[e + 2], r3 = csre[e + 3];
        uint4 v0 = curv[r0.x * 5 + g];
        uint4 v1 = curv[r1.x * 5 + g];
        uint4 v2 = curv[r2.x * 5 + g];
        uint4 v3 = curv[r3.x * 5 + g];
        float w0 = __int_as_float(r0.y), w1 = __int_as_float(r1.y);
        float w2 = __int_as_float(r2.y), w3 = __int_as_float(r3.y);
        acc0 = fmaf(w0, bflo(v0.x), acc0); acc1 = fmaf(w0, bfhi(v0.x), acc1);
        acc2 = fmaf(w0, bflo(v0.y), acc2); acc3 = fmaf(w0, bfhi(v0.y), acc3);
        acc4 = fmaf(w0, bflo(v0.z), acc4); acc5 = fmaf(w0, bfhi(v0.z), acc5);
        acc6 = fmaf(w0, bflo(v0.w), acc6); acc7 = fmaf(w0, bfhi(v0.w), acc7);
        acc0 = fmaf(w1, bflo(v1.x), acc0); acc1 = fmaf(w1, bfhi(v1.x), acc1);
        acc2 = fmaf(w1, bflo(v1.y), acc2); acc3 = fmaf(w1, bfhi(v1.y), acc3);
        acc4 = fmaf(w1, bflo(v1.z), acc4); acc5 = fmaf(w1, bfhi(v1.z), acc5);
        acc6 = fmaf(w1, bflo(v1.w), acc6); acc7 = fmaf(w1, bfhi(v1.w), acc7);
        acc0 = fmaf(w2, bflo(v2.x), acc0); acc1 = fmaf(w2, bfhi(v2.x), acc1);
        acc2 = fmaf(w2, bflo(v2.y), acc2); acc3 = fmaf(w2, bfhi(v2.y), acc3);
        acc4 = fmaf(w2, bflo(v2.z), acc4); acc5 = fmaf(w2, bfhi(v2.z), acc5);
        acc6 = fmaf(w2, bflo(v2.w), acc6); acc7 = fmaf(w2, bfhi(v2.w), acc7);
        acc0 = fmaf(w3, bflo(v3.x), acc0); acc1 = fmaf(w3, bfhi(v3.x), acc1);
        acc2 = fmaf(w3, bflo(v3.y), acc2); acc3 = fmaf(w3, bfhi(v3.y), acc3);
        acc4 = fmaf(w3, bflo(v3.z), acc4); acc5 = fmaf(w3, bfhi(v3.z), acc5);
        acc6 = fmaf(w3, bflo(v3.w), acc6); acc7 = fmaf(w3, bfhi(v3.w), acc7);
    }
    for (; e < end; ++e) {
        int2 r = csre[e];
        float w = __int_as_float(r.y);
        uint4 v = curv[r.x * 5 + g];
        acc0 = fmaf(w, bflo(v.x), acc0); acc1 = fmaf(w, bfhi(v.x), acc1);
        acc2 = fmaf(w, bflo(v.y), acc2); acc3 = fmaf(w, bfhi(v.y), acc3);
        acc4 = fmaf(w, bflo(v.z), acc4); acc5 = fmaf(w, bfhi(v.z), acc5);
        acc6 = fmaf(w, bflo(v.w), acc6); acc7 = fmaf(w, bfhi(v.w), acc7);
    }

    uint4 o;
    o.x = pack2bf(acc0, acc1);
    o.y = pack2bf(acc2, acc3);
    o.z = pack2bf(acc4, acc5);
    o.w = pack2bf(acc6, acc7);
    ((uint4*)nxt)[t] = o;

    float tk = temp[k];
    float4* hp = (float4*)(hidden + (long long)n * OUT_CH + g * 8);
    float4 h0 = hp[0], h1 = hp[1];
    h0.x = fmaf(tk, acc0, h0.x); h0.y = fmaf(tk, acc1, h0.y);
    h0.z = fmaf(tk, acc2, h0.z); h0.w = fmaf(tk, acc3, h0.w);
    h1.x = fmaf(tk, acc4, h1.x); h1.y = fmaf(tk, acc5, h1.y);
    h1.z = fmaf(tk, acc6, h1.z); h1.w = fmaf(tk, acc7, h1.w);
    hp[0] = h0; hp[1] = h1;
}

// In-place log_softmax over the 40-channel rows of d_out.
__launch_bounds__(256)
__global__ void lsm_kernel(float* __restrict__ out) {
    int n = blockIdx.x * blockDim.x + threadIdx.x;
    if (n >= N_NODES) return;
    float4* p = (float4*)(out + (long long)n * OUT_CH);
    float4 v[10];
    float mx = -INFINITY;
    #pragma unroll
    for (int i = 0; i < 10; ++i) {
        v[i] = p[i];
        mx = fmaxf(mx, fmaxf(fmaxf(v[i].x, v[i].y), fmaxf(v[i].z, v[i].w)));
    }
    float sum = 0.f;
    #pragma unroll
    for (int i = 0; i < 10; ++i) {
        sum += expf(v[i].x - mx) + expf(v[i].y - mx) + expf(v[i].z - mx) + expf(v[i].w - mx);
    }
    float l = mx + logf(sum);
    #pragma unroll
    for (int i = 0; i < 10; ++i) {
        v[i].x -= l; v[i].y -= l; v[i].z -= l; v[i].w -= l;
        p[i] = v[i];
    }
}

extern "C" void kernel_launch(void* const* d_in, const int* in_sizes, int n_in,
                              void* d_out, int out_size, void* d_ws, size_t ws_size,
                              hipStream_t stream) {
    const float* x     = (const float*)d_in[0];
    const int*   ei    = (const int*)d_in[1];
    const float* W1    = (const float*)d_in[2];
    const float* b1    = (const float*)d_in[3];
    const float* W2    = (const float*)d_in[4];
    const float* b2    = (const float*)d_in[5];
    const float* gamma = (const float*)d_in[6];
    const float* beta  = (const float*)d_in[7];
    const float* mean  = (const float*)d_in[8];
    const float* var   = (const float*)d_in[9];
    const float* temp  = (const float*)d_in[10];
    float* out = (float*)d_out;

    char* ws = (char*)d_ws;
    int*   flag   = (int*)(ws + OFF_FLAG);
    int*   deg    = (int*)(ws + OFF_DEG);
    int*   rowptr = (int*)(ws + OFF_ROWPTR);
    float* dinv   = (float*)(ws + OFF_DINV);
    int*   bsum   = (int*)(ws + OFF_BSUM);
    int*   bscan  = (int*)(ws + OFF_BSCAN);
    int*   rank   = (int*)(ws + OFF_RANK);
    int2*  csre   = (int2*)(ws + OFF_CSRE);
    unsigned short* curb = (unsigned short*)(ws + OFF_CURB);
    unsigned short* nxtb = (unsigned short*)(ws + OFF_NXTB);

    int gridE = (N_EDGES + 255) / 256;
    int gridN = (N_NODES + 255) / 256;

    detect_kernel<<<1, 64, 0, stream>>>((const unsigned int*)ei, flag);
    zero_deg_kernel<<<gridN, 256, 0, stream>>>(deg);
    deg_rank_kernel<<<gridE, 256, 0, stream>>>(ei, flag, deg, rank);
    scan_reduce_kernel<<<NB_SCAN, 256, 0, stream>>>(deg, bsum);
    scan_bsums_kernel<<<1, 512, 0, stream>>>(bsum, bscan);
    scan_final_kernel<<<NB_SCAN, 256, 0, stream>>>(deg, bscan, rowptr);
    finalize_kernel<<<gridN, 256, 0, stream>>>(deg, dinv);
    fill_kernel<<<gridE, 256, 0, stream>>>(ei, flag, dinv, rowptr, rank, csre);

    stem_kernel<<<(N_NODES + 127) / 128, 256, 0, stream>>>(x, W1, b1, W2, b2, gamma, beta,
                                                           mean, var, temp, curb, out);

    unsigned short* cur = curb;
    unsigned short* nxt = nxtb;
    for (int k = 0; k < K_HOPS; ++k) {
        gather_kernel<<<(N_NODES * 5 + 255) / 256, 256, 0, stream>>>(
            rowptr, csre, cur, nxt, out, dinv, temp, k + 1);
        unsigned short* t2 = cur; cur = nxt; nxt = t2;
    }

    lsm_kernel<<<gridN, 256, 0, stream>>>(out);
}